// Round 14
// baseline (239.159 us; speedup 1.0000x reference)
//
#include <hip/hip_runtime.h>
#include <hip/hip_bf16.h>
#include <hip/hip_fp8.h>

#define NN 100000
#define NE 3200000
#define FIN 128
#define FH 64
#define FO 64
#define NG 128
#define NP 392        // partitions of 256 nodes
#define PSH 8
#define PMASK 255
#define ECAP 9216     // staging capacity per partition (true edges: 8192 +/- 90)
#define OCAP 11264    // padded csr capacity per partition
#define XPAD 136      // bf16 row pad for K=128 tiles
#define HPAD 72       // bf16 row pad for K=64 tiles

typedef unsigned short ushort_t;
typedef unsigned char u8;
typedef __attribute__((ext_vector_type(8))) short bf16x8;
typedef __attribute__((ext_vector_type(4))) float f32x4;

__device__ __forceinline__ float bf2f(ushort_t u) {
  unsigned v = ((unsigned)u) << 16;
  float f;
  __builtin_memcpy(&f, &v, 4);
  return f;
}
__device__ __forceinline__ ushort_t f2bf(float f) {
  __hip_bfloat16 b = __float2bfloat16(f);
  ushort_t u;
  __builtin_memcpy(&u, &b, 2);
  return u;
}

// fp8 e4m3 (OCP) encode/decode via gfx950 hw cvt
__device__ __forceinline__ float fp8dec(u8 b) {
#if __has_builtin(__builtin_amdgcn_cvt_f32_fp8)
  return __builtin_amdgcn_cvt_f32_fp8((int)b, 0);
#else
  __hip_fp8_e4m3 t; t.__x = b; return (float)t;
#endif
}
__device__ __forceinline__ unsigned fp8pk(float a, float b) {
#if __has_builtin(__builtin_amdgcn_cvt_pk_fp8_f32)
  return (unsigned)__builtin_amdgcn_cvt_pk_fp8_f32(a, b, 0, false);
#else
  __hip_fp8_e4m3 ta(a), tb(b);
  return (unsigned)ta.__x | ((unsigned)tb.__x << 8);
#endif
}

// ---------------- init: cursors, out, fp8 sentinels, root search, W transposes ----------------
__global__ void k_init(int* __restrict__ pcur, float* __restrict__ out,
                       const int* __restrict__ batch, int* __restrict__ root_idx,
                       int* __restrict__ gcnt,
                       u8* __restrict__ ps8A, u8* __restrict__ ps8B,
                       const float* __restrict__ W1, const float* __restrict__ W2,
                       ushort_t* __restrict__ wt1, ushort_t* __restrict__ wt2) {
  int i = blockIdx.x * blockDim.x + threadIdx.x;
  if (i < NP) pcur[i] = 0;
  if (i < NG * (FO + FH)) out[i] = 0.0f;
  if (i < FH) {  // zero the sentinel message row (node NN)
    ps8A[(long)NN * FH + i] = 0;
    ps8B[(long)NN * FH + i] = 0;
  }
  if (i < FH * FIN) {  // wt1[f][k] = bf16(W1[k][f])
    int f = i >> 7, k = i & 127;
    wt1[i] = f2bf(W1[k * FH + f]);
  }
  if (i < FH * FO) {   // wt2[f][k] = bf16(W2[k][f])
    int f = i >> 6, k = i & 63;
    wt2[i] = f2bf(W2[k * FO + f]);
  }
  if (i < NG) {
    int g = i;
    int lo = 0, hi = NN;
    while (lo < hi) { int m = (lo + hi) >> 1; if (batch[m] < g) lo = m + 1; else hi = m; }
    int a = lo;
    lo = a; hi = NN;
    while (lo < hi) { int m = (lo + hi) >> 1; if (batch[m] < g + 1) lo = m + 1; else hi = m; }
    int b = lo;
    gcnt[g] = b - a;
    root_idx[g] = (b > a) ? a : (NN - 1);
  }
}

// ---------------- two-phase block-local scatter (1024 thr) ----------------
__global__ __launch_bounds__(1024) void k_pscatter(const int* __restrict__ ei,
                                                   int* __restrict__ pcur,
                                                   int* __restrict__ part_e) {
  __shared__ int lbase[NP];
  __shared__ int lcur[NP];
  const int EPB = NE / 256;  // 12500
  int base = blockIdx.x * EPB;
  int tid = threadIdx.x;
  for (int i = tid; i < NP; i += 1024) { lbase[i] = 0; lcur[i] = 0; }
  __syncthreads();
  for (int i = tid; i < EPB; i += 1024) atomicAdd(&lbase[ei[NE + base + i] >> PSH], 1);
  __syncthreads();
  for (int i = tid; i < NP; i += 1024) {
    int c = lbase[i];
    lbase[i] = c ? (i * ECAP + atomicAdd(&pcur[i], c)) : 0;
  }
  __syncthreads();
  for (int i = tid; i < EPB; i += 1024) {
    int s = ei[base + i];
    int d = ei[NE + base + i];
    int p = d >> PSH;
    int pos = atomicAdd(&lcur[p], 1);
    part_e[lbase[p] + pos] = (s << PSH) | (d & PMASK);
  }
}

// ---------------- per-partition LDS counting sort -> PADDED csr (x16) ----------------
__global__ __launch_bounds__(256) void k_psort(const int* __restrict__ part_e,
                                               const int* __restrict__ pcur,
                                               int* __restrict__ rowptr,
                                               int* __restrict__ rend,
                                               float* __restrict__ dinv,
                                               int* __restrict__ csr_src) {
  __shared__ int ew[ECAP];    // 36 KB
  __shared__ int cnt[256];
  __shared__ int pref[256];
  int p = blockIdx.x, tid = threadIdx.x;
  int pb = p * ECAP;
  int ob = p * OCAP;
  int m = pcur[p];
  for (int i = tid; i < m; i += 256) ew[i] = part_e[pb + i];
  cnt[tid] = 0;
  __syncthreads();
  for (int i = tid; i < m; i += 256) atomicAdd(&cnt[ew[i] & PMASK], 1);
  __syncthreads();
  int deg = cnt[tid];
  int pc = (deg + 15) & ~15;
  pref[tid] = pc;
  __syncthreads();
  for (int d = 1; d < 256; d <<= 1) {
    int t = (tid >= d) ? pref[tid - d] : 0;
    __syncthreads();
    pref[tid] += t;
    __syncthreads();
  }
  int excl = pref[tid] - pc;
  int n = (p << PSH) + tid;
  if (n < NN) {
    rowptr[n] = ob + excl;
    rend[n] = ob + excl + pc;
    dinv[n] = rsqrtf((float)deg + 1.0f);
  }
  for (int j = deg; j < pc; ++j) csr_src[ob + excl + j] = NN;
  __syncthreads();
  pref[tid] = excl;
  __syncthreads();
  for (int i = tid; i < m; i += 256) {
    int w = ew[i];
    int pos = atomicAdd(&pref[w & PMASK], 1);
    csr_src[ob + pos] = w >> PSH;
  }
}

// ---------------- GEMM1 (MFMA): ps1 = fp8((x @ W1) * dinv) ----------------
__global__ __launch_bounds__(256) void k_gemm1(const float* __restrict__ x,
                                               const ushort_t* __restrict__ wt1,
                                               const float* __restrict__ dinv,
                                               u8* __restrict__ ps8) {
  __shared__ ushort_t Xs[64 * XPAD];
  __shared__ ushort_t Ws[64 * XPAD];
  int tid = threadIdx.x;
  long n0 = (long)blockIdx.x * 64;
  int nvalid = (int)(NN - n0);
  if (nvalid > 64) nvalid = 64;
  for (int idx = tid; idx < 64 * 32; idx += 256) {
    int r = idx >> 5, c4 = (idx & 31) * 4;
    if (r < nvalid) {
      float4 v = *(const float4*)(x + (n0 + r) * FIN + c4);
      ushort4 o;
      o.x = f2bf(v.x); o.y = f2bf(v.y); o.z = f2bf(v.z); o.w = f2bf(v.w);
      *(ushort4*)&Xs[r * XPAD + c4] = o;
    }
  }
  for (int idx = tid; idx < 64 * 16; idx += 256) {
    int r = idx >> 4, c8 = (idx & 15) * 8;
    *(ushort4*)&Ws[r * XPAD + c8]     = *(const ushort4*)(wt1 + r * FIN + c8);
    *(ushort4*)&Ws[r * XPAD + c8 + 4] = *(const ushort4*)(wt1 + r * FIN + c8 + 4);
  }
  __syncthreads();
  int w = tid >> 6, l = tid & 63;
  int nb = w * 16;
  int arow = l & 15, koff = (l >> 4) * 8;
  f32x4 acc0 = {0.f, 0.f, 0.f, 0.f}, acc1 = acc0, acc2 = acc0, acc3 = acc0;
  #pragma unroll
  for (int ks = 0; ks < 4; ++ks) {
    bf16x8 a  = *(const bf16x8*)&Xs[(nb + arow) * XPAD + ks * 32 + koff];
    bf16x8 b0 = *(const bf16x8*)&Ws[(arow +  0) * XPAD + ks * 32 + koff];
    bf16x8 b1 = *(const bf16x8*)&Ws[(arow + 16) * XPAD + ks * 32 + koff];
    bf16x8 b2 = *(const bf16x8*)&Ws[(arow + 32) * XPAD + ks * 32 + koff];
    bf16x8 b3 = *(const bf16x8*)&Ws[(arow + 48) * XPAD + ks * 32 + koff];
    acc0 = __builtin_amdgcn_mfma_f32_16x16x32_bf16(a, b0, acc0, 0, 0, 0);
    acc1 = __builtin_amdgcn_mfma_f32_16x16x32_bf16(a, b1, acc1, 0, 0, 0);
    acc2 = __builtin_amdgcn_mfma_f32_16x16x32_bf16(a, b2, acc2, 0, 0, 0);
    acc3 = __builtin_amdgcn_mfma_f32_16x16x32_bf16(a, b3, acc3, 0, 0, 0);
  }
  int drow = (l >> 4) * 4, dcol = l & 15;
  #pragma unroll
  for (int j = 0; j < 4; ++j) {
    int r = nb + drow + j;
    if (r < nvalid) {
      long n = n0 + r;
      float dn = dinv[n];
      unsigned u01 = fp8pk(acc0[j] * dn, acc1[j] * dn);
      unsigned u23 = fp8pk(acc2[j] * dn, acc3[j] * dn);
      ps8[n * FH +  0 + dcol] = (u8)(u01 & 0xff);
      ps8[n * FH + 16 + dcol] = (u8)((u01 >> 8) & 0xff);
      ps8[n * FH + 32 + dcol] = (u8)(u23 & 0xff);
      ps8[n * FH + 48 + dcol] = (u8)((u23 >> 8) & 0xff);
    }
  }
}

// ---------------- per-graph root projection ----------------
__global__ __launch_bounds__(64) void k_rootproj(const float* __restrict__ x,
                                                 const float* __restrict__ W2,
                                                 const int* __restrict__ root_idx,
                                                 float* __restrict__ rp) {
  __shared__ float xr[FIN];
  int g = blockIdx.x;
  int t = threadIdx.x;
  long r = root_idx[g];
  xr[t]      = fmaxf(x[r * FIN + t], 0.0f);
  xr[t + 64] = fmaxf(x[r * FIN + t + 64], 0.0f);
  __syncthreads();
  float acc = 0.0f;
  #pragma unroll 8
  for (int i = 0; i < FIN; ++i) acc += xr[i] * W2[(FH + i) * FO + t];
  rp[g * FO + t] = acc;
}

// ---------------- exact fp32 h1 for the 128 root nodes ----------------
__global__ __launch_bounds__(256) void k_rootfix(const float* __restrict__ x,
                                                 const float* __restrict__ W1,
                                                 const float* __restrict__ b1,
                                                 const float* __restrict__ dinv,
                                                 const int* __restrict__ root_idx,
                                                 const int* __restrict__ rowptr,
                                                 const int* __restrict__ rend,
                                                 const int* __restrict__ csr_src,
                                                 float* __restrict__ rootH) {
  __shared__ float Ws[FIN * FH];   // 32 KB
  __shared__ float part[4 * FH];
  int g = blockIdx.x, tid = threadIdx.x;
  for (int i = tid; i < FIN * FH; i += 256) Ws[i] = W1[i];
  __syncthreads();
  int rn = root_idx[g];
  int beg = rowptr[rn], end = rend[rn];
  int w = tid >> 6, lane = tid & 63;
  float acc = 0.0f;
  for (int i = beg + w; i < end; i += 4) {
    int s = csr_src[i];
    if (s == NN) continue;
    float y = 0.0f;
    #pragma unroll 8
    for (int k = 0; k < FIN; k += 4) {
      float4 xv = *(const float4*)(x + (long)s * FIN + k);
      y += xv.x * Ws[(k + 0) * FH + lane] + xv.y * Ws[(k + 1) * FH + lane]
         + xv.z * Ws[(k + 2) * FH + lane] + xv.w * Ws[(k + 3) * FH + lane];
    }
    acc += y * dinv[s];
  }
  if (w == 0) {  // self term
    float y = 0.0f;
    #pragma unroll 8
    for (int k = 0; k < FIN; k += 4) {
      float4 xv = *(const float4*)(x + (long)rn * FIN + k);
      y += xv.x * Ws[(k + 0) * FH + lane] + xv.y * Ws[(k + 1) * FH + lane]
         + xv.z * Ws[(k + 2) * FH + lane] + xv.w * Ws[(k + 3) * FH + lane];
    }
    acc += y * dinv[rn];
  }
  part[w * FH + lane] = acc;
  __syncthreads();
  if (tid < FH) {
    float t = part[tid] + part[FH + tid] + part[2 * FH + tid] + part[3 * FH + tid];
    rootH[g * FH + tid] = dinv[rn] * t + b1[tid];
  }
}

// ---------------- per-node aggregation: fp8 gathers (64B rows), fp32 acc ----------------
template <int RELU>
__global__ __launch_bounds__(256) void k_agg(const u8* __restrict__ ps8,
                                             const float* __restrict__ dinv,
                                             const int* __restrict__ rowptr,
                                             const int* __restrict__ rend,
                                             const int* __restrict__ csr_src,
                                             const float* __restrict__ bias,
                                             ushort_t* __restrict__ outb) {
  int lane = threadIdx.x & 63;
  int n = __builtin_amdgcn_readfirstlane(blockIdx.x * 4 + (threadIdx.x >> 6));
  int beg = __builtin_amdgcn_readfirstlane(rowptr[n]);
  int end = __builtin_amdgcn_readfirstlane(rend[n]);
  float acc = fp8dec(ps8[((long)n << 6) + lane]);
  for (int i = beg; i < end; i += 16) {
    int s0 = __builtin_amdgcn_readfirstlane(csr_src[i + 0]);
    int s1 = __builtin_amdgcn_readfirstlane(csr_src[i + 1]);
    int s2 = __builtin_amdgcn_readfirstlane(csr_src[i + 2]);
    int s3 = __builtin_amdgcn_readfirstlane(csr_src[i + 3]);
    int s4 = __builtin_amdgcn_readfirstlane(csr_src[i + 4]);
    int s5 = __builtin_amdgcn_readfirstlane(csr_src[i + 5]);
    int s6 = __builtin_amdgcn_readfirstlane(csr_src[i + 6]);
    int s7 = __builtin_amdgcn_readfirstlane(csr_src[i + 7]);
    int s8 = __builtin_amdgcn_readfirstlane(csr_src[i + 8]);
    int s9 = __builtin_amdgcn_readfirstlane(csr_src[i + 9]);
    int sa = __builtin_amdgcn_readfirstlane(csr_src[i + 10]);
    int sb = __builtin_amdgcn_readfirstlane(csr_src[i + 11]);
    int sc = __builtin_amdgcn_readfirstlane(csr_src[i + 12]);
    int sd = __builtin_amdgcn_readfirstlane(csr_src[i + 13]);
    int se = __builtin_amdgcn_readfirstlane(csr_src[i + 14]);
    int sf = __builtin_amdgcn_readfirstlane(csr_src[i + 15]);
    u8 c0 = ps8[((long)s0 << 6) + lane];
    u8 c1 = ps8[((long)s1 << 6) + lane];
    u8 c2 = ps8[((long)s2 << 6) + lane];
    u8 c3 = ps8[((long)s3 << 6) + lane];
    u8 c4 = ps8[((long)s4 << 6) + lane];
    u8 c5 = ps8[((long)s5 << 6) + lane];
    u8 c6 = ps8[((long)s6 << 6) + lane];
    u8 c7 = ps8[((long)s7 << 6) + lane];
    u8 c8 = ps8[((long)s8 << 6) + lane];
    u8 c9 = ps8[((long)s9 << 6) + lane];
    u8 ca = ps8[((long)sa << 6) + lane];
    u8 cb = ps8[((long)sb << 6) + lane];
    u8 cc = ps8[((long)sc << 6) + lane];
    u8 cd = ps8[((long)sd << 6) + lane];
    u8 ce = ps8[((long)se << 6) + lane];
    u8 cf = ps8[((long)sf << 6) + lane];
    acc += fp8dec(c0); acc += fp8dec(c1); acc += fp8dec(c2); acc += fp8dec(c3);
    acc += fp8dec(c4); acc += fp8dec(c5); acc += fp8dec(c6); acc += fp8dec(c7);
    acc += fp8dec(c8); acc += fp8dec(c9); acc += fp8dec(ca); acc += fp8dec(cb);
    acc += fp8dec(cc); acc += fp8dec(cd); acc += fp8dec(ce); acc += fp8dec(cf);
  }
  float val = dinv[n] * acc + bias[lane];
  if (RELU) val = fmaxf(val, 0.0f);
  outb[((long)n << 6) + lane] = f2bf(val);
}

// ---------------- GEMM2 (MFMA): ps2 = fp8((relu(h1) @ W2[0:64,:] + rp[batch]) * dinv) ----------------
__global__ __launch_bounds__(256) void k_gemm2(const ushort_t* __restrict__ h1,
                                               const ushort_t* __restrict__ wt2,
                                               const float* __restrict__ rp,
                                               const int* __restrict__ batch,
                                               const float* __restrict__ dinv,
                                               u8* __restrict__ ps8) {
  __shared__ ushort_t Hs[64 * HPAD];
  __shared__ ushort_t Ws[64 * HPAD];
  int tid = threadIdx.x;
  long n0 = (long)blockIdx.x * 64;
  int nvalid = (int)(NN - n0);
  if (nvalid > 64) nvalid = 64;
  for (int idx = tid; idx < 64 * 16; idx += 256) {
    int r = idx >> 4, c4 = (idx & 15) * 4;
    if (r < nvalid) {
      ushort4 v = *(const ushort4*)(h1 + (n0 + r) * FH + c4);
      ushort4 o;
      o.x = (v.x & 0x8000) ? 0 : v.x;
      o.y = (v.y & 0x8000) ? 0 : v.y;
      o.z = (v.z & 0x8000) ? 0 : v.z;
      o.w = (v.w & 0x8000) ? 0 : v.w;
      *(ushort4*)&Hs[r * HPAD + c4] = o;
    }
  }
  for (int idx = tid; idx < 64 * 16; idx += 256) {
    int r = idx >> 4, c4 = (idx & 15) * 4;
    *(ushort4*)&Ws[r * HPAD + c4] = *(const ushort4*)(wt2 + r * FH + c4);
  }
  __syncthreads();
  int w = tid >> 6, l = tid & 63;
  int nb = w * 16;
  int arow = l & 15, koff = (l >> 4) * 8;
  f32x4 acc0 = {0.f, 0.f, 0.f, 0.f}, acc1 = acc0, acc2 = acc0, acc3 = acc0;
  #pragma unroll
  for (int ks = 0; ks < 2; ++ks) {
    bf16x8 a  = *(const bf16x8*)&Hs[(nb + arow) * HPAD + ks * 32 + koff];
    bf16x8 b0 = *(const bf16x8*)&Ws[(arow +  0) * HPAD + ks * 32 + koff];
    bf16x8 b1 = *(const bf16x8*)&Ws[(arow + 16) * HPAD + ks * 32 + koff];
    bf16x8 b2 = *(const bf16x8*)&Ws[(arow + 32) * HPAD + ks * 32 + koff];
    bf16x8 b3 = *(const bf16x8*)&Ws[(arow + 48) * HPAD + ks * 32 + koff];
    acc0 = __builtin_amdgcn_mfma_f32_16x16x32_bf16(a, b0, acc0, 0, 0, 0);
    acc1 = __builtin_amdgcn_mfma_f32_16x16x32_bf16(a, b1, acc1, 0, 0, 0);
    acc2 = __builtin_amdgcn_mfma_f32_16x16x32_bf16(a, b2, acc2, 0, 0, 0);
    acc3 = __builtin_amdgcn_mfma_f32_16x16x32_bf16(a, b3, acc3, 0, 0, 0);
  }
  int drow = (l >> 4) * 4, dcol = l & 15;
  #pragma unroll
  for (int j = 0; j < 4; ++j) {
    int r = nb + drow + j;
    if (r < nvalid) {
      long n = n0 + r;
      float dn = dinv[n];
      long rb = (long)batch[n] * FO;
      unsigned u01 = fp8pk((acc0[j] + rp[rb +  0 + dcol]) * dn,
                           (acc1[j] + rp[rb + 16 + dcol]) * dn);
      unsigned u23 = fp8pk((acc2[j] + rp[rb + 32 + dcol]) * dn,
                           (acc3[j] + rp[rb + 48 + dcol]) * dn);
      ps8[n * FH +  0 + dcol] = (u8)(u01 & 0xff);
      ps8[n * FH + 16 + dcol] = (u8)((u01 >> 8) & 0xff);
      ps8[n * FH + 32 + dcol] = (u8)(u23 & 0xff);
      ps8[n * FH + 48 + dcol] = (u8)((u23 >> 8) & 0xff);
    }
  }
}

// ---------------- mean-pool (25 nodes per wave) ----------------
__global__ __launch_bounds__(64) void k_pool(const ushort_t* __restrict__ r,
                                             const int* __restrict__ batch,
                                             float* __restrict__ out) {
  const int PC = 25;
  int lane = threadIdx.x;
  long n0 = (long)blockIdx.x * PC;
  long n1 = n0 + PC;
  if (n1 > NN) n1 = NN;
  if (n0 >= NN) return;
  float acc = 0.0f;
  int cur = batch[n0];
  for (long n = n0; n < n1; ++n) {
    int g = batch[n];
    if (g != cur) {
      atomicAdd(&out[(long)cur * (FO + FH) + lane], acc);
      acc = 0.0f;
      cur = g;
    }
    acc += bf2f(r[n * FH + lane]);
  }
  atomicAdd(&out[(long)cur * (FO + FH) + lane], acc);
}

// ---------------- finalize: root2 from exact fp32 rootH ----------------
__global__ void k_final(float* __restrict__ out, const int* __restrict__ gcnt,
                        const float* __restrict__ rootH) {
  int i = blockIdx.x * blockDim.x + threadIdx.x;
  if (i >= NG * FO) return;
  int g = i >> 6, f = i & 63;
  int c = gcnt[g];
  float inv = 1.0f / fmaxf((float)c, 1.0f);
  out[g * (FO + FH) + f] *= inv;
  out[g * (FO + FH) + FO + f] = (c > 0) ? rootH[g * FH + f] : 0.0f;
}

extern "C" void kernel_launch(void* const* d_in, const int* in_sizes, int n_in,
                              void* d_out, int out_size, void* d_ws, size_t ws_size,
                              hipStream_t stream) {
  const float* x   = (const float*)d_in[0];
  const int*   ei  = (const int*)d_in[1];
  const int*   bat = (const int*)d_in[2];
  const float* W1  = (const float*)d_in[3];
  const float* b1  = (const float*)d_in[4];
  const float* W2  = (const float*)d_in[5];
  const float* b2  = (const float*)d_in[6];
  float* out = (float*)d_out;

  char* p = (char*)d_ws;
  auto carve = [&](size_t bytes) -> void* {
    char* q = p;
    p += (bytes + 511) & ~size_t(511);
    return (void*)q;
  };
  float* dinv    = (float*)carve((size_t)NN * 4);
  int*   pcur    = (int*)carve((size_t)NP * 4);
  int*   part_e  = (int*)carve((size_t)NP * ECAP * 4);
  int*   rowptr  = (int*)carve((size_t)NN * 4);
  int*   rend    = (int*)carve((size_t)NN * 4);
  int*   csr_src = (int*)carve((size_t)NP * OCAP * 4);
  u8*    ps8A    = (u8*)carve((size_t)(NN + 1) * FH);      // fp8 + sentinel
  u8*    ps8B    = (u8*)carve((size_t)(NN + 1) * FH);      // fp8 + sentinel
  ushort_t* bufB = (ushort_t*)carve((size_t)NN * FH * 2);  // h1 bf16
  ushort_t* bufD = (ushort_t*)carve((size_t)NN * FH * 2);  // r  bf16
  int*   root_i  = (int*)carve((size_t)NG * 4);
  int*   gcnt    = (int*)carve((size_t)NG * 4);
  float* rp      = (float*)carve((size_t)NG * FO * 4);
  float* rootH   = (float*)carve((size_t)NG * FH * 4);
  ushort_t* wt1  = (ushort_t*)carve((size_t)FH * FIN * 2);
  ushort_t* wt2  = (ushort_t*)carve((size_t)FH * FO * 2);

  const int GB = (NN + 63) / 64;  // 1563
  k_init<<<96, 256, 0, stream>>>(pcur, out, bat, root_i, gcnt, ps8A, ps8B, W1, W2, wt1, wt2);
  k_pscatter<<<256, 1024, 0, stream>>>(ei, pcur, part_e);
  k_psort<<<NP, 256, 0, stream>>>(part_e, pcur, rowptr, rend, dinv, csr_src);
  k_gemm1<<<GB, 256, 0, stream>>>(x, wt1, dinv, ps8A);
  k_rootproj<<<NG, 64, 0, stream>>>(x, W2, root_i, rp);
  k_rootfix<<<NG, 256, 0, stream>>>(x, W1, b1, dinv, root_i, rowptr, rend, csr_src, rootH);
  k_agg<0><<<NN / 4, 256, 0, stream>>>(ps8A, dinv, rowptr, rend, csr_src, b1, bufB);
  k_gemm2<<<GB, 256, 0, stream>>>(bufB, wt2, rp, bat, dinv, ps8B);
  k_agg<1><<<NN / 4, 256, 0, stream>>>(ps8B, dinv, rowptr, rend, csr_src, b2, bufD);
  k_pool<<<(NN + 24) / 25, 64, 0, stream>>>(bufD, bat, out);
  k_final<<<(NG * FO + 255) / 256, 256, 0, stream>>>(out, gcnt, rootH);
}

// Round 15
// 215.549 us; speedup vs baseline: 1.1095x; 1.1095x over previous
//
#include <hip/hip_runtime.h>
#include <hip/hip_bf16.h>

#define NN 100000
#define NE 3200000
#define FIN 128
#define FH 64
#define FO 64
#define NG 128
#define NP 392        // partitions of 256 nodes
#define PSH 8
#define PMASK 255
#define ECAP 9216     // staging capacity per partition (true edges: 8192 +/- 90)
#define OCAP 11264    // padded csr capacity per partition
#define XPAD 136      // bf16 row pad for K=128 tiles
#define HPAD 72       // bf16 row pad for K=64 tiles

typedef unsigned short ushort_t;
typedef __attribute__((ext_vector_type(8))) short bf16x8;
typedef __attribute__((ext_vector_type(4))) float f32x4;

__device__ __forceinline__ float bf2f(ushort_t u) {
  unsigned v = ((unsigned)u) << 16;
  float f;
  __builtin_memcpy(&f, &v, 4);
  return f;
}
__device__ __forceinline__ ushort_t f2bf(float f) {
  __hip_bfloat16 b = __float2bfloat16(f);
  ushort_t u;
  __builtin_memcpy(&u, &b, 2);
  return u;
}

// ---------------- init: cursors, out, sentinels, root search, W transposes ----------------
__global__ void k_init(int* __restrict__ pcur, float* __restrict__ out,
                       const int* __restrict__ batch, int* __restrict__ root_idx,
                       int* __restrict__ gcnt,
                       ushort_t* __restrict__ psA, ushort_t* __restrict__ psB,
                       const float* __restrict__ W1, const float* __restrict__ W2,
                       ushort_t* __restrict__ wt1, ushort_t* __restrict__ wt2) {
  int i = blockIdx.x * blockDim.x + threadIdx.x;
  if (i < NP) pcur[i] = 0;
  if (i < NG * (FO + FH)) out[i] = 0.0f;
  if (i < FH) {  // zero the sentinel message row (node NN)
    psA[(long)NN * FH + i] = 0;
    psB[(long)NN * FH + i] = 0;
  }
  if (i < FH * FIN) {  // wt1[f][k] = bf16(W1[k][f])
    int f = i >> 7, k = i & 127;
    wt1[i] = f2bf(W1[k * FH + f]);
  }
  if (i < FH * FO) {   // wt2[f][k] = bf16(W2[k][f]), rows 0..63 of W2
    int f = i >> 6, k = i & 63;
    wt2[i] = f2bf(W2[k * FO + f]);
  }
  if (i < NG) {
    int g = i;
    int lo = 0, hi = NN;
    while (lo < hi) { int m = (lo + hi) >> 1; if (batch[m] < g) lo = m + 1; else hi = m; }
    int a = lo;
    lo = a; hi = NN;
    while (lo < hi) { int m = (lo + hi) >> 1; if (batch[m] < g + 1) lo = m + 1; else hi = m; }
    int b = lo;
    gcnt[g] = b - a;
    root_idx[g] = (b > a) ? a : (NN - 1);
  }
}

// ---------------- two-phase block-local scatter (1024 thr) ----------------
__global__ __launch_bounds__(1024) void k_pscatter(const int* __restrict__ ei,
                                                   int* __restrict__ pcur,
                                                   int* __restrict__ part_e) {
  __shared__ int lbase[NP];
  __shared__ int lcur[NP];
  const int EPB = NE / 256;  // 12500
  int base = blockIdx.x * EPB;
  int tid = threadIdx.x;
  for (int i = tid; i < NP; i += 1024) { lbase[i] = 0; lcur[i] = 0; }
  __syncthreads();
  for (int i = tid; i < EPB; i += 1024) atomicAdd(&lbase[ei[NE + base + i] >> PSH], 1);
  __syncthreads();
  for (int i = tid; i < NP; i += 1024) {
    int c = lbase[i];
    lbase[i] = c ? (i * ECAP + atomicAdd(&pcur[i], c)) : 0;
  }
  __syncthreads();
  for (int i = tid; i < EPB; i += 1024) {
    int s = ei[base + i];
    int d = ei[NE + base + i];
    int p = d >> PSH;
    int pos = atomicAdd(&lcur[p], 1);
    part_e[lbase[p] + pos] = (s << PSH) | (d & PMASK);
  }
}

// ---------------- per-partition LDS counting sort -> PADDED csr (x16), 512 thr ----------------
__global__ __launch_bounds__(512) void k_psort(const int* __restrict__ part_e,
                                               const int* __restrict__ pcur,
                                               int* __restrict__ rowptr,
                                               int* __restrict__ rend,
                                               float* __restrict__ dinv,
                                               int* __restrict__ csr_src) {
  __shared__ int ew[ECAP];    // 36 KB
  __shared__ int cnt[256];
  __shared__ int pref[256];
  int p = blockIdx.x, tid = threadIdx.x;
  int pb = p * ECAP;
  int ob = p * OCAP;
  int m = pcur[p];
  for (int i = tid; i < m; i += 512) ew[i] = part_e[pb + i];
  if (tid < 256) cnt[tid] = 0;
  __syncthreads();
  for (int i = tid; i < m; i += 512) atomicAdd(&cnt[ew[i] & PMASK], 1);
  __syncthreads();
  if (tid < 256) pref[tid] = (cnt[tid] + 15) & ~15;  // padded slot sizes
  __syncthreads();
  for (int d = 1; d < 256; d <<= 1) {
    int t = (tid >= d && tid < 256) ? pref[tid - d] : 0;
    __syncthreads();
    if (tid < 256) pref[tid] += t;
    __syncthreads();
  }
  if (tid < 256) {
    int deg = cnt[tid];
    int pc = (deg + 15) & ~15;
    int excl = pref[tid] - pc;
    int n = (p << PSH) + tid;
    if (n < NN) {
      rowptr[n] = ob + excl;
      rend[n] = ob + excl + pc;
      dinv[n] = rsqrtf((float)deg + 1.0f);
    }
    for (int j = deg; j < pc; ++j) csr_src[ob + excl + j] = NN;
  }
  __syncthreads();
  if (tid < 256) pref[tid] -= (cnt[tid] + 15) & ~15;  // back to exclusive = cursor
  __syncthreads();
  for (int i = tid; i < m; i += 512) {
    int w = ew[i];
    int pos = atomicAdd(&pref[w & PMASK], 1);
    csr_src[ob + pos] = w >> PSH;
  }
}

// ---------------- GEMM1 (MFMA): ps1 = bf16((x @ W1) * dinv) ----------------
__global__ __launch_bounds__(256) void k_gemm1(const float* __restrict__ x,
                                               const ushort_t* __restrict__ wt1,
                                               const float* __restrict__ dinv,
                                               ushort_t* __restrict__ ps) {
  __shared__ ushort_t Xs[64 * XPAD];
  __shared__ ushort_t Ws[64 * XPAD];
  int tid = threadIdx.x;
  long n0 = (long)blockIdx.x * 64;
  int nvalid = (int)(NN - n0);
  if (nvalid > 64) nvalid = 64;
  for (int idx = tid; idx < 64 * 32; idx += 256) {
    int r = idx >> 5, c4 = (idx & 31) * 4;
    if (r < nvalid) {
      float4 v = *(const float4*)(x + (n0 + r) * FIN + c4);
      ushort4 o;
      o.x = f2bf(v.x); o.y = f2bf(v.y); o.z = f2bf(v.z); o.w = f2bf(v.w);
      *(ushort4*)&Xs[r * XPAD + c4] = o;
    }
  }
  for (int idx = tid; idx < 64 * 16; idx += 256) {
    int r = idx >> 4, c8 = (idx & 15) * 8;
    *(ushort4*)&Ws[r * XPAD + c8]     = *(const ushort4*)(wt1 + r * FIN + c8);
    *(ushort4*)&Ws[r * XPAD + c8 + 4] = *(const ushort4*)(wt1 + r * FIN + c8 + 4);
  }
  __syncthreads();
  int w = tid >> 6, l = tid & 63;
  int nb = w * 16;
  int arow = l & 15, koff = (l >> 4) * 8;
  f32x4 acc0 = {0.f, 0.f, 0.f, 0.f}, acc1 = acc0, acc2 = acc0, acc3 = acc0;
  #pragma unroll
  for (int ks = 0; ks < 4; ++ks) {
    bf16x8 a  = *(const bf16x8*)&Xs[(nb + arow) * XPAD + ks * 32 + koff];
    bf16x8 b0 = *(const bf16x8*)&Ws[(arow +  0) * XPAD + ks * 32 + koff];
    bf16x8 b1 = *(const bf16x8*)&Ws[(arow + 16) * XPAD + ks * 32 + koff];
    bf16x8 b2 = *(const bf16x8*)&Ws[(arow + 32) * XPAD + ks * 32 + koff];
    bf16x8 b3 = *(const bf16x8*)&Ws[(arow + 48) * XPAD + ks * 32 + koff];
    acc0 = __builtin_amdgcn_mfma_f32_16x16x32_bf16(a, b0, acc0, 0, 0, 0);
    acc1 = __builtin_amdgcn_mfma_f32_16x16x32_bf16(a, b1, acc1, 0, 0, 0);
    acc2 = __builtin_amdgcn_mfma_f32_16x16x32_bf16(a, b2, acc2, 0, 0, 0);
    acc3 = __builtin_amdgcn_mfma_f32_16x16x32_bf16(a, b3, acc3, 0, 0, 0);
  }
  int drow = (l >> 4) * 4, dcol = l & 15;
  #pragma unroll
  for (int j = 0; j < 4; ++j) {
    int r = nb + drow + j;
    if (r < nvalid) {
      long n = n0 + r;
      float dn = dinv[n];
      ps[n * FH +  0 + dcol] = f2bf(acc0[j] * dn);
      ps[n * FH + 16 + dcol] = f2bf(acc1[j] * dn);
      ps[n * FH + 32 + dcol] = f2bf(acc2[j] * dn);
      ps[n * FH + 48 + dcol] = f2bf(acc3[j] * dn);
    }
  }
}

// ---------------- per-graph root projection ----------------
__global__ __launch_bounds__(64) void k_rootproj(const float* __restrict__ x,
                                                 const float* __restrict__ W2,
                                                 const int* __restrict__ root_idx,
                                                 float* __restrict__ rp) {
  __shared__ float xr[FIN];
  int g = blockIdx.x;
  int t = threadIdx.x;
  long r = root_idx[g];
  xr[t]      = fmaxf(x[r * FIN + t], 0.0f);
  xr[t + 64] = fmaxf(x[r * FIN + t + 64], 0.0f);
  __syncthreads();
  float acc = 0.0f;
  #pragma unroll 8
  for (int i = 0; i < FIN; ++i) acc += xr[i] * W2[(FH + i) * FO + t];
  rp[g * FO + t] = acc;
}

// ---------------- per-node aggregation: single 16-deep loop over padded edges ----------------
template <int RELU>
__global__ __launch_bounds__(256) void k_agg(const ushort_t* __restrict__ ps,
                                             const float* __restrict__ dinv,
                                             const int* __restrict__ rowptr,
                                             const int* __restrict__ rend,
                                             const int* __restrict__ csr_src,
                                             const float* __restrict__ bias,
                                             ushort_t* __restrict__ outb) {
  int lane = threadIdx.x & 63;
  int n = __builtin_amdgcn_readfirstlane(blockIdx.x * 4 + (threadIdx.x >> 6));
  int beg = __builtin_amdgcn_readfirstlane(rowptr[n]);
  int end = __builtin_amdgcn_readfirstlane(rend[n]);
  float acc = bf2f(ps[((long)n << 6) + lane]);
  for (int i = beg; i < end; i += 16) {
    int s0 = __builtin_amdgcn_readfirstlane(csr_src[i + 0]);
    int s1 = __builtin_amdgcn_readfirstlane(csr_src[i + 1]);
    int s2 = __builtin_amdgcn_readfirstlane(csr_src[i + 2]);
    int s3 = __builtin_amdgcn_readfirstlane(csr_src[i + 3]);
    int s4 = __builtin_amdgcn_readfirstlane(csr_src[i + 4]);
    int s5 = __builtin_amdgcn_readfirstlane(csr_src[i + 5]);
    int s6 = __builtin_amdgcn_readfirstlane(csr_src[i + 6]);
    int s7 = __builtin_amdgcn_readfirstlane(csr_src[i + 7]);
    int s8 = __builtin_amdgcn_readfirstlane(csr_src[i + 8]);
    int s9 = __builtin_amdgcn_readfirstlane(csr_src[i + 9]);
    int sa = __builtin_amdgcn_readfirstlane(csr_src[i + 10]);
    int sb = __builtin_amdgcn_readfirstlane(csr_src[i + 11]);
    int sc = __builtin_amdgcn_readfirstlane(csr_src[i + 12]);
    int sd = __builtin_amdgcn_readfirstlane(csr_src[i + 13]);
    int se = __builtin_amdgcn_readfirstlane(csr_src[i + 14]);
    int sf = __builtin_amdgcn_readfirstlane(csr_src[i + 15]);
    float v0 = bf2f(ps[((long)s0 << 6) + lane]);
    float v1 = bf2f(ps[((long)s1 << 6) + lane]);
    float v2 = bf2f(ps[((long)s2 << 6) + lane]);
    float v3 = bf2f(ps[((long)s3 << 6) + lane]);
    float v4 = bf2f(ps[((long)s4 << 6) + lane]);
    float v5 = bf2f(ps[((long)s5 << 6) + lane]);
    float v6 = bf2f(ps[((long)s6 << 6) + lane]);
    float v7 = bf2f(ps[((long)s7 << 6) + lane]);
    float v8 = bf2f(ps[((long)s8 << 6) + lane]);
    float v9 = bf2f(ps[((long)s9 << 6) + lane]);
    float va = bf2f(ps[((long)sa << 6) + lane]);
    float vb = bf2f(ps[((long)sb << 6) + lane]);
    float vc = bf2f(ps[((long)sc << 6) + lane]);
    float vd = bf2f(ps[((long)sd << 6) + lane]);
    float ve = bf2f(ps[((long)se << 6) + lane]);
    float vf = bf2f(ps[((long)sf << 6) + lane]);
    acc += v0; acc += v1; acc += v2; acc += v3;
    acc += v4; acc += v5; acc += v6; acc += v7;
    acc += v8; acc += v9; acc += va; acc += vb;
    acc += vc; acc += vd; acc += ve; acc += vf;
  }
  float val = dinv[n] * acc + bias[lane];
  if (RELU) val = fmaxf(val, 0.0f);
  outb[((long)n << 6) + lane] = f2bf(val);
}

// ---------------- GEMM2 (MFMA): ps2 = bf16((relu(h1) @ W2[0:64,:] + rp[batch]) * dinv) ----------------
__global__ __launch_bounds__(256) void k_gemm2(const ushort_t* __restrict__ h1,
                                               const ushort_t* __restrict__ wt2,
                                               const float* __restrict__ rp,
                                               const int* __restrict__ batch,
                                               const float* __restrict__ dinv,
                                               ushort_t* __restrict__ ps2) {
  __shared__ ushort_t Hs[64 * HPAD];
  __shared__ ushort_t Ws[64 * HPAD];
  int tid = threadIdx.x;
  long n0 = (long)blockIdx.x * 64;
  int nvalid = (int)(NN - n0);
  if (nvalid > 64) nvalid = 64;
  for (int idx = tid; idx < 64 * 16; idx += 256) {
    int r = idx >> 4, c4 = (idx & 15) * 4;
    if (r < nvalid) {
      ushort4 v = *(const ushort4*)(h1 + (n0 + r) * FH + c4);
      ushort4 o;
      o.x = (v.x & 0x8000) ? 0 : v.x;
      o.y = (v.y & 0x8000) ? 0 : v.y;
      o.z = (v.z & 0x8000) ? 0 : v.z;
      o.w = (v.w & 0x8000) ? 0 : v.w;
      *(ushort4*)&Hs[r * HPAD + c4] = o;
    }
  }
  for (int idx = tid; idx < 64 * 16; idx += 256) {
    int r = idx >> 4, c4 = (idx & 15) * 4;
    *(ushort4*)&Ws[r * HPAD + c4] = *(const ushort4*)(wt2 + r * FH + c4);
  }
  __syncthreads();
  int w = tid >> 6, l = tid & 63;
  int nb = w * 16;
  int arow = l & 15, koff = (l >> 4) * 8;
  f32x4 acc0 = {0.f, 0.f, 0.f, 0.f}, acc1 = acc0, acc2 = acc0, acc3 = acc0;
  #pragma unroll
  for (int ks = 0; ks < 2; ++ks) {
    bf16x8 a  = *(const bf16x8*)&Hs[(nb + arow) * HPAD + ks * 32 + koff];
    bf16x8 b0 = *(const bf16x8*)&Ws[(arow +  0) * HPAD + ks * 32 + koff];
    bf16x8 b1 = *(const bf16x8*)&Ws[(arow + 16) * HPAD + ks * 32 + koff];
    bf16x8 b2 = *(const bf16x8*)&Ws[(arow + 32) * HPAD + ks * 32 + koff];
    bf16x8 b3 = *(const bf16x8*)&Ws[(arow + 48) * HPAD + ks * 32 + koff];
    acc0 = __builtin_amdgcn_mfma_f32_16x16x32_bf16(a, b0, acc0, 0, 0, 0);
    acc1 = __builtin_amdgcn_mfma_f32_16x16x32_bf16(a, b1, acc1, 0, 0, 0);
    acc2 = __builtin_amdgcn_mfma_f32_16x16x32_bf16(a, b2, acc2, 0, 0, 0);
    acc3 = __builtin_amdgcn_mfma_f32_16x16x32_bf16(a, b3, acc3, 0, 0, 0);
  }
  int drow = (l >> 4) * 4, dcol = l & 15;
  #pragma unroll
  for (int j = 0; j < 4; ++j) {
    int r = nb + drow + j;
    if (r < nvalid) {
      long n = n0 + r;
      float dn = dinv[n];
      long rb = (long)batch[n] * FO;
      ps2[n * FH +  0 + dcol] = f2bf((acc0[j] + rp[rb +  0 + dcol]) * dn);
      ps2[n * FH + 16 + dcol] = f2bf((acc1[j] + rp[rb + 16 + dcol]) * dn);
      ps2[n * FH + 32 + dcol] = f2bf((acc2[j] + rp[rb + 32 + dcol]) * dn);
      ps2[n * FH + 48 + dcol] = f2bf((acc3[j] + rp[rb + 48 + dcol]) * dn);
    }
  }
}

// ---------------- mean-pool (25 nodes per wave) ----------------
__global__ __launch_bounds__(64) void k_pool(const ushort_t* __restrict__ r,
                                             const int* __restrict__ batch,
                                             float* __restrict__ out) {
  const int PC = 25;
  int lane = threadIdx.x;
  long n0 = (long)blockIdx.x * PC;
  long n1 = n0 + PC;
  if (n1 > NN) n1 = NN;
  if (n0 >= NN) return;
  float acc = 0.0f;
  int cur = batch[n0];
  for (long n = n0; n < n1; ++n) {
    int g = batch[n];
    if (g != cur) {
      atomicAdd(&out[(long)cur * (FO + FH) + lane], acc);
      acc = 0.0f;
      cur = g;
    }
    acc += bf2f(r[n * FH + lane]);
  }
  atomicAdd(&out[(long)cur * (FO + FH) + lane], acc);
}

// ---------------- finalize ----------------
__global__ void k_final(float* __restrict__ out, const int* __restrict__ gcnt,
                        const int* __restrict__ root_idx, const ushort_t* __restrict__ h1full) {
  int i = blockIdx.x * blockDim.x + threadIdx.x;
  if (i >= NG * FO) return;
  int g = i >> 6, f = i & 63;
  int c = gcnt[g];
  float inv = 1.0f / fmaxf((float)c, 1.0f);
  out[g * (FO + FH) + f] *= inv;
  out[g * (FO + FH) + FO + f] = (c > 0) ? bf2f(h1full[(long)root_idx[g] * FH + f]) : 0.0f;
}

extern "C" void kernel_launch(void* const* d_in, const int* in_sizes, int n_in,
                              void* d_out, int out_size, void* d_ws, size_t ws_size,
                              hipStream_t stream) {
  const float* x   = (const float*)d_in[0];
  const int*   ei  = (const int*)d_in[1];
  const int*   bat = (const int*)d_in[2];
  const float* W1  = (const float*)d_in[3];
  const float* b1  = (const float*)d_in[4];
  const float* W2  = (const float*)d_in[5];
  const float* b2  = (const float*)d_in[6];
  float* out = (float*)d_out;

  char* p = (char*)d_ws;
  auto carve = [&](size_t bytes) -> void* {
    char* q = p;
    p += (bytes + 511) & ~size_t(511);
    return (void*)q;
  };
  float* dinv    = (float*)carve((size_t)NN * 4);
  int*   pcur    = (int*)carve((size_t)NP * 4);
  int*   part_e  = (int*)carve((size_t)NP * ECAP * 4);
  int*   rowptr  = (int*)carve((size_t)NN * 4);
  int*   rend    = (int*)carve((size_t)NN * 4);
  int*   csr_src = (int*)carve((size_t)NP * OCAP * 4);
  ushort_t* psA  = (ushort_t*)carve((size_t)(NN + 1) * FH * 2);  // +sentinel
  ushort_t* psB  = (ushort_t*)carve((size_t)(NN + 1) * FH * 2);  // +sentinel
  ushort_t* bufB = (ushort_t*)carve((size_t)NN * FH * 2);
  ushort_t* bufD = (ushort_t*)carve((size_t)NN * FH * 2);
  int*   root_i  = (int*)carve((size_t)NG * 4);
  int*   gcnt    = (int*)carve((size_t)NG * 4);
  float* rp      = (float*)carve((size_t)NG * FO * 4);
  ushort_t* wt1  = (ushort_t*)carve((size_t)FH * FIN * 2);
  ushort_t* wt2  = (ushort_t*)carve((size_t)FH * FO * 2);

  const int GB = (NN + 63) / 64;  // 1563
  k_init<<<96, 256, 0, stream>>>(pcur, out, bat, root_i, gcnt, psA, psB, W1, W2, wt1, wt2);
  k_pscatter<<<256, 1024, 0, stream>>>(ei, pcur, part_e);
  k_psort<<<NP, 512, 0, stream>>>(part_e, pcur, rowptr, rend, dinv, csr_src);
  k_gemm1<<<GB, 256, 0, stream>>>(x, wt1, dinv, psA);
  k_rootproj<<<NG, 64, 0, stream>>>(x, W2, root_i, rp);
  k_agg<0><<<NN / 4, 256, 0, stream>>>(psA, dinv, rowptr, rend, csr_src, b1, bufB);
  k_gemm2<<<GB, 256, 0, stream>>>(bufB, wt2, rp, bat, dinv, psB);
  k_agg<1><<<NN / 4, 256, 0, stream>>>(psB, dinv, rowptr, rend, csr_src, b2, bufD);
  k_pool<<<(NN + 24) / 25, 64, 0, stream>>>(bufD, bat, out);
  k_final<<<(NG * FO + 255) / 256, 256, 0, stream>>>(out, gcnt, root_i, bufB);
}